// Round 6
// baseline (24.311 us; speedup 1.0000x reference)
//
#include <hip/hip_runtime.h>

// RouteExactNgramMemory forward — fused single kernel, v2.
// Shapes: B=2, T=1024, HIDDEN=1024, BITS=4, R=256 routes, ALPHABET=16,
// MEM_DIM=16, NGRAMS=(2,3).  out flat = [B, T, 2*256*16] f32.
//
// Block = (b, t-chunk of 16 consecutive t, route-group of 32), 512 threads.
//   bid = b(1) | tchunk(6) | rgrp(3)  -> bid&7 = rgrp = XCD id (L2 pinning).
// Phase 1: block computes the 18x32 codes it needs from q into LDS
//   (nontemporal loads: q is read-once, keep L2 for the tables).
// Phase 2: each thread does 4 t-positions x 2 orders = 8 independent 16B
//   gathers (MLP=8); all stores wave-contiguous nontemporal (1KB/wave).

#define BB 2
#define TT 1024
#define RR 256

using f4 = __attribute__((ext_vector_type(4))) float;

__global__ __launch_bounds__(512) void fused_kernel(
    const float* __restrict__ q,
    const float* __restrict__ t2,
    const float* __restrict__ t3,
    float* __restrict__ out) {
    int bid   = blockIdx.x;
    int rgrp  = bid & 7;
    int tch   = (bid >> 3) & 63;
    int b     = bid >> 9;
    int t0    = tch << 4;          // 16 consecutive t's per block
    int rbase = rgrp << 5;

    __shared__ unsigned char lcode[18 * 32];   // [ti][rlo], t = t0-2+ti

    int tx = threadIdx.x;

    // ---- Phase 1: 576 codes from q (each: one float4 -> 4 sign bits) ----
    const f4* qv = reinterpret_cast<const f4*>(q);   // [B,T,256] f4
#pragma unroll
    for (int i = 0; i < 2; ++i) {
        int item = tx + (i << 9);
        if (item < 576) {
            int ti  = item >> 5;
            int rlo = item & 31;
            int t   = t0 - 2 + ti;
            unsigned char code = 0;
            if (t >= 0) {
                f4 v = __builtin_nontemporal_load(
                    qv + (size_t)(b * TT + t) * RR + rbase + rlo);
                code = (v.x > 0.0f ? 1u : 0u)
                     | (v.y > 0.0f ? 2u : 0u)
                     | (v.z > 0.0f ? 4u : 0u)
                     | (v.w > 0.0f ? 8u : 0u);
            }
            lcode[ti * 32 + rlo] = code;
        }
    }
    __syncthreads();

    // ---- Phase 2: gathers ----
    int part = tx & 3;
    int rlo  = (tx >> 2) & 31;
    int tlo  = tx >> 7;            // [0,4), wave-uniform
    int r    = rbase + rlo;

    // 6 consecutive codes for this thread's 4 t's (t = t0 + tlo*4 + k)
    unsigned char cc[6];
#pragma unroll
    for (int j = 0; j < 6; ++j)
        cc[j] = lcode[(tlo * 4 + j) * 32 + rlo];

    const f4* t2v = reinterpret_cast<const f4*>(t2);
    const f4* t3v = reinterpret_cast<const f4*>(t3);
    f4 z = {0.f, 0.f, 0.f, 0.f};
    f4 v2[4], v3[4];
#pragma unroll
    for (int k = 0; k < 4; ++k) {
        int t  = t0 + tlo * 4 + k;         // wave-uniform
        int a2 = cc[k], a1 = cc[k + 1], a0 = cc[k + 2];
        v2[k] = (t >= 1)
            ? t2v[(((r << 8) + a1 + (a0 << 4)) << 2) + part] : z;
        v3[k] = (t >= 2)
            ? t3v[(((r << 12) + a2 + (a1 << 4) + (a0 << 8)) << 2) + part] : z;
    }

    f4* ov = reinterpret_cast<f4*>(out);
#pragma unroll
    for (int k = 0; k < 4; ++k) {
        int t = t0 + tlo * 4 + k;
        size_t base = (((size_t)(b * TT + t) * 2) * RR + r) * 4 + part;
        __builtin_nontemporal_store(v2[k], ov + base);
        __builtin_nontemporal_store(v3[k], ov + base + RR * 4);
    }
}

extern "C" void kernel_launch(void* const* d_in, const int* in_sizes, int n_in,
                              void* d_out, int out_size, void* d_ws, size_t ws_size,
                              hipStream_t stream) {
    const float* q  = (const float*)d_in[0];   // [2,1024,1024] f32
    const float* t2 = (const float*)d_in[1];   // [65536,16] f32
    const float* t3 = (const float*)d_in[2];   // [1048576,16] f32
    float* out = (float*)d_out;                // [2,1024,8192] f32

    // 2 b x 64 t-chunks x 8 route-groups = 1024 blocks x 512 threads
    fused_kernel<<<1024, 512, 0, stream>>>(q, t2, t3, out);
}

// Round 7
// 24.034 us; speedup vs baseline: 1.0115x; 1.0115x over previous
//
#include <hip/hip_runtime.h>

// RouteExactNgramMemory forward — fused single kernel (best config, R5).
// Shapes: B=2, T=1024, HIDDEN=1024, BITS=4, R=256 routes, ALPHABET=16,
// MEM_DIM=16, NGRAMS=(2,3).  out flat = [B, T, 2*256*16] f32.
//
// Block = (b, t-chunk of 8 consecutive t, route-group of 32), 256 threads.
//   bid = b(1) | tchunk(7) | rgrp(3)  -> bid&7 = rgrp = XCD id (L2 pinning:
//   per-XCD unique table slice ~3.8MB fits the 4MB XCD L2).
// Phase 1: block computes the 10x32 codes it needs from q into LDS.
// Phase 2: each thread does 4 t-positions x 2 orders = 8 independent 16B
//   gathers (MLP=8); all stores wave-contiguous nontemporal (1KB/wave).

#define BB 2
#define TT 1024
#define RR 256

using f4 = __attribute__((ext_vector_type(4))) float;

__global__ __launch_bounds__(256) void fused_kernel(
    const float* __restrict__ q,
    const float* __restrict__ t2,
    const float* __restrict__ t3,
    float* __restrict__ out) {
    int bid   = blockIdx.x;
    int rgrp  = bid & 7;
    int tch   = (bid >> 3) & 127;
    int b     = bid >> 10;
    int t0    = tch << 3;          // 8 consecutive t's per block
    int rbase = rgrp << 5;

    __shared__ unsigned char lcode[10 * 32];   // [ti][rlo], t = t0-2+ti

    int tx = threadIdx.x;

    // ---- Phase 1: 320 codes from q (each: one float4 -> 4 sign bits) ----
    const f4* qv = reinterpret_cast<const f4*>(q);   // [B,T,256] f4
#pragma unroll
    for (int i = 0; i < 2; ++i) {
        int item = tx + (i << 8);
        if (item < 320) {
            int ti  = item >> 5;
            int rlo = item & 31;
            int t   = t0 - 2 + ti;
            unsigned char code = 0;
            if (t >= 0) {
                f4 v = qv[(size_t)(b * TT + t) * RR + rbase + rlo];
                code = (v.x > 0.0f ? 1u : 0u)
                     | (v.y > 0.0f ? 2u : 0u)
                     | (v.z > 0.0f ? 4u : 0u)
                     | (v.w > 0.0f ? 8u : 0u);
            }
            lcode[ti * 32 + rlo] = code;
        }
    }
    __syncthreads();

    // ---- Phase 2: gathers ----
    int part = tx & 3;
    int rlo  = (tx >> 2) & 31;
    int tlo  = tx >> 7;            // 0/1, wave-uniform
    int r    = rbase + rlo;

    // 6 consecutive codes for this thread's 4 t's (t = t0 + tlo*4 + k)
    unsigned char cc[6];
#pragma unroll
    for (int j = 0; j < 6; ++j)
        cc[j] = lcode[(tlo * 4 + j) * 32 + rlo];

    const f4* t2v = reinterpret_cast<const f4*>(t2);
    const f4* t3v = reinterpret_cast<const f4*>(t3);
    f4 z = {0.f, 0.f, 0.f, 0.f};
    f4 v2[4], v3[4];
#pragma unroll
    for (int k = 0; k < 4; ++k) {
        int t  = t0 + tlo * 4 + k;         // wave-uniform
        int a2 = cc[k], a1 = cc[k + 1], a0 = cc[k + 2];
        v2[k] = (t >= 1)
            ? t2v[(((r << 8) + a1 + (a0 << 4)) << 2) + part] : z;
        v3[k] = (t >= 2)
            ? t3v[(((r << 12) + a2 + (a1 << 4) + (a0 << 8)) << 2) + part] : z;
    }

    f4* ov = reinterpret_cast<f4*>(out);
#pragma unroll
    for (int k = 0; k < 4; ++k) {
        int t = t0 + tlo * 4 + k;
        size_t base = (((size_t)(b * TT + t) * 2) * RR + r) * 4 + part;
        __builtin_nontemporal_store(v2[k], ov + base);
        __builtin_nontemporal_store(v3[k], ov + base + RR * 4);
    }
}

extern "C" void kernel_launch(void* const* d_in, const int* in_sizes, int n_in,
                              void* d_out, int out_size, void* d_ws, size_t ws_size,
                              hipStream_t stream) {
    const float* q  = (const float*)d_in[0];   // [2,1024,1024] f32
    const float* t2 = (const float*)d_in[1];   // [65536,16] f32
    const float* t3 = (const float*)d_in[2];   // [1048576,16] f32
    float* out = (float*)d_out;                // [2,1024,8192] f32

    // 2 b x 128 t-chunks x 8 route-groups = 2048 blocks x 256 threads
    fused_kernel<<<2048, 256, 0, stream>>>(q, t2, t3, out);
}